// Round 13
// baseline (397.612 us; speedup 1.0000x reference)
//
#include <hip/hip_runtime.h>
#include <hip/hip_bf16.h>
#include <math.h>

// AttentionDownSample: fm [8,128,256,256] f32, Wq/Wk [32,128] f32
// out [8,128,128,128] f32.
//
// r13: read-fm-once bf16 register stash, re-shaped for PHASE STAGGERING.
// Session invariant r4-r12: ~18 us per block-round regardless of design —
// bursty phase-M loads then a long load-free VALU phase => HBM duty ~20%.
// Fix: small blocks, small register footprint, high CO-RESIDENCY so blocks
// at different phases overlap loads with compute:
//   - 256 thr = 32 positions x 8 half-wave groups (16 ch/thread)
//   - stash: v as 32 bf16x2 regs + window-sum u as 8 bf16x2 regs (40 total)
//   - r-dim in 4 quarters: only qa[8]/qh[8] live -> peak ~75 VGPR
//   - weights via per-lane vector loads (L1-resident 32 KB; group is
//     half-wave so s_load is impossible; 2 addrs/wave broadcast fine)
//   - LDS 12.5 KB; __launch_bounds__(256,5): budget 102 -> NO spill
//   - grid 4096 (16 blocks/CU), 5 resident/CU staggered
//
// Per position: u[c]=v0+v1+v2+v3; Q[r]=sum_c WqT'[c][r]u[c] (0.25/sqrt32
// folded); t[c]=sum_r Q[r]WkT[c][r]; logit_s=sum_c t[c]v_s[c];
// out[c]=sum_s softmax(logit)_s v_s[c]. Linear in every r/c split.

typedef unsigned int uint32;

__device__ __forceinline__ uint32 pack2(float x, float y) {
  union { __hip_bfloat162 h; uint32 u; } cvt;
  cvt.h = __float22bfloat162_rn(make_float2(x, y));
  return cvt.u;
}
__device__ __forceinline__ float2 unpack2(uint32 u) {
  float2 r;
  r.x = __uint_as_float(u << 16);
  r.y = __uint_as_float(u & 0xffff0000u);
  return r;
}

__global__ __launch_bounds__(256) void wt_kernel(const float* __restrict__ Wq,
                                                 const float* __restrict__ Wk,
                                                 float* __restrict__ ws) {
  int t = blockIdx.x * 256 + threadIdx.x;  // 4096 threads, one (c,r) each
  if (t < 4096) {
    int c = t >> 5, r = t & 31;
    ws[c * 32 + r]        = Wq[r * 128 + c] * (0.25f / sqrtf(32.0f));
    ws[4096 + c * 32 + r] = Wk[r * 128 + c];
  }
}

__global__ __launch_bounds__(256, 5)
void attn_main(const float* __restrict__ fm,
               const float* __restrict__ ws,
               float* __restrict__ out) {
  __shared__ float Qt[4 * 8 * 32];    // [k][r8][p] 4 KB, reused per quarter
  __shared__ float Qf[32 * 32];       // [r][p]     4 KB
  __shared__ float lbuf[8 * 32 * 4];  // [g][p][s]  4 KB
  __shared__ float abuf[32 * 4];      // [p][s]     0.5 KB

  const int tid = threadIdx.x;
  const int p   = tid & 31;      // position 0..31
  const int g   = tid >> 5;      // channel group 0..7 (16 ch) — half-wave
  const int blk = blockIdx.x;    // 4096 = 8 b * 128 h * 4 wt
  const int w0  = (blk & 3) * 32;
  const int h   = (blk >> 2) & 127;
  const int b   = blk >> 9;
  const int cb  = g * 16;

  const float* gbase = fm + ((size_t)(b * 128 + cb)) * 65536 +
                       (size_t)(2 * h) * 256 + 2 * (w0 + p);
  const float* wqv = ws + cb * 32;          // WqT'[c][r] (per-lane loads)
  const float* wkv = ws + 4096 + cb * 32;   // WkT[c][r]

  // ---- phase M: fm read EXACTLY once -> bf16x2 stash (v and window-sum u) --
  uint32 pka[16], pkb[16], pku[8];
#pragma unroll
  for (int ii = 0; ii < 8; ++ii) {
    const float2 va0 = *(const float2*)(gbase + (size_t)(2 * ii) * 65536);
    const float2 vb0 = *(const float2*)(gbase + (size_t)(2 * ii) * 65536 + 256);
    const float2 va1 = *(const float2*)(gbase + (size_t)(2 * ii + 1) * 65536);
    const float2 vb1 = *(const float2*)(gbase + (size_t)(2 * ii + 1) * 65536 + 256);
    pka[2 * ii]     = pack2(va0.x, va0.y);
    pkb[2 * ii]     = pack2(vb0.x, vb0.y);
    pka[2 * ii + 1] = pack2(va1.x, va1.y);
    pkb[2 * ii + 1] = pack2(vb1.x, vb1.y);
    pku[ii] = pack2((va0.x + va0.y) + (vb0.x + vb0.y),
                    (va1.x + va1.y) + (vb1.x + vb1.y));
  }

  // ---- pass 1: Q in 4 r-quarters (qa[8] live; tree 8->4->1 via LDS) ----
#pragma unroll
  for (int q = 0; q < 4; ++q) {
    float qa[8];
#pragma unroll
    for (int j = 0; j < 8; ++j) qa[j] = 0.f;
#pragma unroll
    for (int ii = 0; ii < 8; ++ii) {
      const float2 uu = unpack2(pku[ii]);
      const float4 wa0 = *(const float4*)(wqv + (2 * ii) * 32 + q * 8);
      const float4 wa1 = *(const float4*)(wqv + (2 * ii) * 32 + q * 8 + 4);
      const float4 wb0 = *(const float4*)(wqv + (2 * ii + 1) * 32 + q * 8);
      const float4 wb1 = *(const float4*)(wqv + (2 * ii + 1) * 32 + q * 8 + 4);
      qa[0] = fmaf(wa0.x, uu.x, qa[0]); qa[1] = fmaf(wa0.y, uu.x, qa[1]);
      qa[2] = fmaf(wa0.z, uu.x, qa[2]); qa[3] = fmaf(wa0.w, uu.x, qa[3]);
      qa[4] = fmaf(wa1.x, uu.x, qa[4]); qa[5] = fmaf(wa1.y, uu.x, qa[5]);
      qa[6] = fmaf(wa1.z, uu.x, qa[6]); qa[7] = fmaf(wa1.w, uu.x, qa[7]);
      qa[0] = fmaf(wb0.x, uu.y, qa[0]); qa[1] = fmaf(wb0.y, uu.y, qa[1]);
      qa[2] = fmaf(wb0.z, uu.y, qa[2]); qa[3] = fmaf(wb0.w, uu.y, qa[3]);
      qa[4] = fmaf(wb1.x, uu.y, qa[4]); qa[5] = fmaf(wb1.y, uu.y, qa[5]);
      qa[6] = fmaf(wb1.z, uu.y, qa[6]); qa[7] = fmaf(wb1.w, uu.y, qa[7]);
    }
    // tree: groups 4..7 write, groups 0..3 add (wave-uniform branches)
    if (g >= 4) {
#pragma unroll
      for (int j = 0; j < 8; ++j) Qt[(g - 4) * 256 + j * 32 + p] = qa[j];
    }
    __syncthreads();
    if (g < 4) {
#pragma unroll
      for (int j = 0; j < 8; ++j) Qt[g * 256 + j * 32 + p] += qa[j];
    }
    __syncthreads();
    // gather: thread (g,p) finalizes row r=g of this quarter
    Qf[(q * 8 + g) * 32 + p] = (Qt[g * 32 + p] + Qt[256 + g * 32 + p]) +
                               (Qt[512 + g * 32 + p] + Qt[768 + g * 32 + p]);
    __syncthreads();
  }

  // ---- pass 2: logits in 4 r-quarters (qh[8] live) ----
  float l0 = 0.f, l1 = 0.f, l2 = 0.f, l3 = 0.f;
#pragma unroll
  for (int q = 0; q < 4; ++q) {
    float qh[8];
#pragma unroll
    for (int r = 0; r < 8; ++r) qh[r] = Qf[(q * 8 + r) * 32 + p];
#pragma unroll
    for (int i = 0; i < 16; ++i) {
      const float4 k0 = *(const float4*)(wkv + i * 32 + q * 8);
      const float4 k1 = *(const float4*)(wkv + i * 32 + q * 8 + 4);
      float t0 = qh[0] * k0.x;
      float t1 = qh[1] * k0.y;
      t0 = fmaf(qh[2], k0.z, t0); t1 = fmaf(qh[3], k0.w, t1);
      t0 = fmaf(qh[4], k1.x, t0); t1 = fmaf(qh[5], k1.y, t1);
      t0 = fmaf(qh[6], k1.z, t0); t1 = fmaf(qh[7], k1.w, t1);
      const float tv = t0 + t1;
      const float2 va = unpack2(pka[i]);
      const float2 vb = unpack2(pkb[i]);
      l0 = fmaf(tv, va.x, l0);
      l1 = fmaf(tv, va.y, l1);
      l2 = fmaf(tv, vb.x, l2);
      l3 = fmaf(tv, vb.y, l3);
    }
  }
  *(float4*)(lbuf + (g * 32 + p) * 4) = make_float4(l0, l1, l2, l3);
  __syncthreads();

  // ---- softmax (half-wave combines 8 groups, broadcasts via abuf) ----
  if (tid < 32) {
    float L0 = 0.f, L1 = 0.f, L2 = 0.f, L3 = 0.f;
#pragma unroll
    for (int k = 0; k < 8; ++k) {
      const float4 s = *(const float4*)(lbuf + (k * 32 + tid) * 4);
      L0 += s.x; L1 += s.y; L2 += s.z; L3 += s.w;
    }
    const float mx = fmaxf(fmaxf(L0, L1), fmaxf(L2, L3));
    const float e0 = __expf(L0 - mx), e1 = __expf(L1 - mx);
    const float e2 = __expf(L2 - mx), e3 = __expf(L3 - mx);
    const float inv = 1.0f / ((e0 + e1) + (e2 + e3));
    *(float4*)(abuf + tid * 4) =
        make_float4(e0 * inv, e1 * inv, e2 * inv, e3 * inv);
  }
  __syncthreads();
  const float4 at = *(const float4*)(abuf + p * 4);

  // ---- pass 3: weighted window sum from stash -> out (coalesced) ----
  {
    float* op = out + ((size_t)(b * 128 + cb)) * 16384 + h * 128 + w0 + p;
#pragma unroll
    for (int i = 0; i < 16; ++i) {
      const float2 va = unpack2(pka[i]);
      const float2 vb = unpack2(pkb[i]);
      op[(size_t)i * 16384] =
          fmaf(at.x, va.x, fmaf(at.y, va.y, fmaf(at.z, vb.x, at.w * vb.y)));
    }
  }
}

extern "C" void kernel_launch(void* const* d_in, const int* in_sizes, int n_in,
                              void* d_out, int out_size, void* d_ws, size_t ws_size,
                              hipStream_t stream) {
  const float* fm = (const float*)d_in[0];
  const float* Wq = (const float*)d_in[1];
  const float* Wk = (const float*)d_in[2];
  float* outp = (float*)d_out;
  float* ws = (float*)d_ws;

  wt_kernel<<<16, 256, 0, stream>>>(Wq, Wk, ws);
  attn_main<<<4096, 256, 0, stream>>>(fm, ws, outp);
}

// Round 14
// 198.231 us; speedup vs baseline: 2.0058x; 2.0058x over previous
//
#include <hip/hip_runtime.h>
#include <hip/hip_bf16.h>
#include <math.h>

// AttentionDownSample: fm [8,128,256,256] f32, Wq/Wk [32,128] f32
// out [8,128,128,128] f32.
//
// r14: stash lives in LDS, not VGPRs. r8/r9/r11/r13 all spilled because the
// allocator's LDS-driven occupancy heuristic squeezes VGPRs below any big
// register stash. LDS has no such heuristic: each thread parks its V-slice
// (16 ch x 4 window vals, packed bf16x2) in thread-private LDS cells — a
// software-managed spill that needs no barriers. Register peak ~55 -> no
// spill even at a 64-reg budget. Small tiles + 40 KB LDS = 4 blocks/CU,
// 16 waves, cross-block phase stagger for HBM duty cycle.
//   - block 256 thr = 32 positions x 8 half-wave ch-groups (16 ch/thread)
//   - weights: per-lane float4 vector loads (L1-hot 32 KB, vmcnt-counted;
//     2 unique addrs/wave -> broadcast; NO scalar-pipe serialization)
//   - fm read exactly once, fused with pass-1 Q accumulation
//   - Q reduce: __shfl_xor(32) within wave, then 2-stage LDS tree (8 KB,
//     aliased later by lbuf/abuf)
// Per position: u[c]=v0+v1+v2+v3 (f32); Q[r]=sum_c WqT'[c][r]u[c]
// (0.25/sqrt32 folded); t[c]=sum_r Q[r]WkT[c][r]; logit_s=sum_c t[c]v_s[c];
// out[c]=sum_s softmax(logit)_s v_s[c].

typedef unsigned int uint32;

__device__ __forceinline__ uint32 pack2(float x, float y) {
  union { __hip_bfloat162 h; uint32 u; } cvt;
  cvt.h = __float22bfloat162_rn(make_float2(x, y));
  return cvt.u;
}
__device__ __forceinline__ float2 unpack2(uint32 u) {
  float2 r;
  r.x = __uint_as_float(u << 16);
  r.y = __uint_as_float(u & 0xffff0000u);
  return r;
}

__global__ __launch_bounds__(256) void wt_kernel(const float* __restrict__ Wq,
                                                 const float* __restrict__ Wk,
                                                 float* __restrict__ ws) {
  int t = blockIdx.x * 256 + threadIdx.x;  // 4096 threads, one (c,r) each
  if (t < 4096) {
    int c = t >> 5, r = t & 31;
    ws[c * 32 + r]        = Wq[r * 128 + c] * (0.25f / sqrtf(32.0f));
    ws[4096 + c * 32 + r] = Wk[r * 128 + c];
  }
}

__global__ __launch_bounds__(256)
void attn_main(const float* __restrict__ fm,
               const float* __restrict__ ws,
               float* __restrict__ out) {
  __shared__ uint32 Vlds[128 * 32 * 2];  // 32 KB [c][p][2]: thread-private stash
  __shared__ float Qt[2 * 32 * 32];      // 8 KB Q-tree; aliased lbuf+abuf later

  const int tid = threadIdx.x;
  const int p   = tid & 31;     // position 0..31
  const int g   = tid >> 5;     // half-wave channel group 0..7 (16 ch)
  const int w   = tid >> 6;     // wave 0..3
  const bool lowhalf = (tid & 32) == 0;

  const int blk = blockIdx.x;   // 4096 = 8 b * 128 h * 4 wt
  const int w0  = (blk & 3) * 32;
  const int h   = (blk >> 2) & 127;
  const int b   = blk >> 9;
  const int cb  = g * 16;

  const float* gbase = fm + ((size_t)(b * 128 + cb)) * 65536 +
                       (size_t)(2 * h) * 256 + 2 * (w0 + p);
  const float* wqv = ws + cb * 32;          // WqT'[c][r]
  const float* wkv = ws + 4096 + cb * 32;   // WkT[c][r]

  // ---- fused phase M + pass 1: fm read ONCE; V -> LDS stash; Q accum ----
  float qa[32];
#pragma unroll
  for (int r = 0; r < 32; ++r) qa[r] = 0.f;
#pragma unroll
  for (int i = 0; i < 16; ++i) {
    const float2 va = *(const float2*)(gbase + (size_t)i * 65536);        // row0
    const float2 vb = *(const float2*)(gbase + (size_t)i * 65536 + 256);  // row1
    Vlds[(cb + i) * 64 + 2 * p]     = pack2(va.x, va.y);
    Vlds[(cb + i) * 64 + 2 * p + 1] = pack2(vb.x, vb.y);
    const float u = (va.x + va.y) + (vb.x + vb.y);  // f32-exact window sum
#pragma unroll
    for (int rr = 0; rr < 32; rr += 4) {
      const float4 wv = *(const float4*)(wqv + i * 32 + rr);
      qa[rr + 0] = fmaf(wv.x, u, qa[rr + 0]);
      qa[rr + 1] = fmaf(wv.y, u, qa[rr + 1]);
      qa[rr + 2] = fmaf(wv.z, u, qa[rr + 2]);
      qa[rr + 3] = fmaf(wv.w, u, qa[rr + 3]);
    }
  }

  // ---- Q reduce: pair-combine inside wave (shfl), then 2-stage LDS tree ----
#pragma unroll
  for (int r = 0; r < 32; ++r) qa[r] += __shfl_xor(qa[r], 32);
  // 4 wave-partials -> Qt[0] = w0+w2, Qt[1] = w1+w3 (low half-wave only)
  if (w >= 2 && lowhalf) {
#pragma unroll
    for (int r = 0; r < 32; ++r) Qt[(w - 2) * 1024 + r * 32 + p] = qa[r];
  }
  __syncthreads();
  if (w < 2 && lowhalf) {
#pragma unroll
    for (int r = 0; r < 32; ++r) Qt[w * 1024 + r * 32 + p] += qa[r];
  }
  __syncthreads();

  // ---- pass 2: logits (V from LDS stash, weights float4 from L1) ----
  float qh[32];
#pragma unroll
  for (int r = 0; r < 32; ++r)
    qh[r] = Qt[r * 32 + p] + Qt[1024 + r * 32 + p];

  float l0 = 0.f, l1 = 0.f, l2 = 0.f, l3 = 0.f;
#pragma unroll
  for (int i = 0; i < 16; ++i) {
    float t0 = 0.f, t1 = 0.f;
#pragma unroll
    for (int rr = 0; rr < 32; rr += 4) {
      const float4 kv = *(const float4*)(wkv + i * 32 + rr);
      t0 = fmaf(qh[rr + 0], kv.x, t0);
      t1 = fmaf(qh[rr + 1], kv.y, t1);
      t0 = fmaf(qh[rr + 2], kv.z, t0);
      t1 = fmaf(qh[rr + 3], kv.w, t1);
    }
    const float tv = t0 + t1;
    const float2 va = unpack2(Vlds[(cb + i) * 64 + 2 * p]);
    const float2 vb = unpack2(Vlds[(cb + i) * 64 + 2 * p + 1]);
    l0 = fmaf(tv, va.x, l0);
    l1 = fmaf(tv, va.y, l1);
    l2 = fmaf(tv, vb.x, l2);
    l3 = fmaf(tv, vb.y, l3);
  }
  __syncthreads();  // qh reads done -> Qt reusable as lbuf/abuf

  // ---- combine logits across the 8 groups + softmax ----
  float* lbuf = Qt;          // [8 g][32 p][4 s] = 1024 floats
  float* abuf = Qt + 1024;   // [32 p][4 s]
  *(float4*)(lbuf + (g * 32 + p) * 4) = make_float4(l0, l1, l2, l3);
  __syncthreads();
  if (tid < 32) {
    float L0 = 0.f, L1 = 0.f, L2 = 0.f, L3 = 0.f;
#pragma unroll
    for (int k = 0; k < 8; ++k) {
      const float4 s = *(const float4*)(lbuf + (k * 32 + tid) * 4);
      L0 += s.x; L1 += s.y; L2 += s.z; L3 += s.w;
    }
    const float mx = fmaxf(fmaxf(L0, L1), fmaxf(L2, L3));
    const float e0 = __expf(L0 - mx), e1 = __expf(L1 - mx);
    const float e2 = __expf(L2 - mx), e3 = __expf(L3 - mx);
    const float inv = 1.0f / ((e0 + e1) + (e2 + e3));
    *(float4*)(abuf + tid * 4) =
        make_float4(e0 * inv, e1 * inv, e2 * inv, e3 * inv);
  }
  __syncthreads();
  const float4 at = *(const float4*)(abuf + p * 4);

  // ---- pass 3: weighted window sum from LDS stash -> out (coalesced) ----
  {
    float* op = out + ((size_t)(b * 128 + cb)) * 16384 + h * 128 + w0 + p;
#pragma unroll
    for (int i = 0; i < 16; ++i) {
      const float2 va = unpack2(Vlds[(cb + i) * 64 + 2 * p]);
      const float2 vb = unpack2(Vlds[(cb + i) * 64 + 2 * p + 1]);
      op[(size_t)i * 16384] =
          fmaf(at.x, va.x, fmaf(at.y, va.y, fmaf(at.z, vb.x, at.w * vb.y)));
    }
  }
}

extern "C" void kernel_launch(void* const* d_in, const int* in_sizes, int n_in,
                              void* d_out, int out_size, void* d_ws, size_t ws_size,
                              hipStream_t stream) {
  const float* fm = (const float*)d_in[0];
  const float* Wq = (const float*)d_in[1];
  const float* Wk = (const float*)d_in[2];
  float* outp = (float*)d_out;
  float* ws = (float*)d_ws;

  wt_kernel<<<16, 256, 0, stream>>>(Wq, Wk, ws);
  attn_main<<<4096, 256, 0, stream>>>(fm, ws, outp);
}

// Round 15
// 187.612 us; speedup vs baseline: 2.1193x; 1.0566x over previous
//
#include <hip/hip_runtime.h>
#include <hip/hip_bf16.h>
#include <math.h>

// AttentionDownSample: fm [8,128,256,256] f32, Wq/Wk [32,128] f32
// out [8,128,128,128] f32.
//
// r15: read-fm-once with the stash in SMALL LDS, and every phase homogeneous.
// Session law (r5-r14): VGPR<=64 && LDS<=~34KB && 256-thr => runs at its
// static occupancy; VGPR>64 designs get squeezed/spilled by the allocator.
// So: 16-position blocks, all cross-phase state in 34 KB LDS, peak register
// need ~55 (safe under ANY budget), grid 8192 (32 blocks/CU stagger).
//   ph1 STREAM (the only fm reader): load float2 pairs -> f32 window sum u ->
//        ds_write ubuf; pack v -> bf16x2 -> ds_write vstash. No weights/FMA.
//   ph2 GEMM1: Q[r][p] = sum_c WqT'[c][r]*u[c][p]; c split 2-way, partials
//        combined in LDS. Weights: per-lane float4 (L1-hot 32 KB, vmcnt).
//   ph3 fused t+logits: qh[32] regs from LDS; per ch: t=sum_r qh*WkT (float4
//        loads), logits += t*v (v from vstash via ds_read). No SMEM in loops.
//   ph4 softmax (16 lanes), ph5 out = attn.v from vstash.
// Strides padded (17 / 33) => no >=4-way bank conflicts.
// u is f32-exact (pooled path); v bf16 (absmax 0.0156 proven, thr 0.0569).

typedef unsigned int uint32;

__device__ __forceinline__ uint32 pack2(float x, float y) {
  union { __hip_bfloat162 h; uint32 u; } cvt;
  cvt.h = __float22bfloat162_rn(make_float2(x, y));
  return cvt.u;
}
__device__ __forceinline__ float2 unpack2(uint32 u) {
  float2 r;
  r.x = __uint_as_float(u << 16);
  r.y = __uint_as_float(u & 0xffff0000u);
  return r;
}

__global__ __launch_bounds__(256) void wt_kernel(const float* __restrict__ Wq,
                                                 const float* __restrict__ Wk,
                                                 float* __restrict__ ws) {
  int t = blockIdx.x * 256 + threadIdx.x;  // 4096 threads, one (c,r) each
  if (t < 4096) {
    int c = t >> 5, r = t & 31;
    ws[c * 32 + r]        = Wq[r * 128 + c] * (0.25f / sqrtf(32.0f));
    ws[4096 + c * 32 + r] = Wk[r * 128 + c];
  }
}

__global__ __launch_bounds__(256)
void attn_main(const float* __restrict__ fm,
               const float* __restrict__ ws,
               float* __restrict__ out) {
  __shared__ float  ubuf[128 * 17];    // u[c][p], stride 17 (8.5 KB)
  __shared__ uint32 vstash[128 * 33];  // v[c][2p+j] bf16x2, stride 33 (16.9 KB)
  __shared__ float  Qpart[2 * 32 * 17]; // [ch][r][p] stride 17 (4.25 KB)
  __shared__ float  lbuf[16 * 16 * 4];  // [g][p][s] (4 KB)
  __shared__ float  abuf[16 * 4];       // [p][s] (256 B)

  const int tid = threadIdx.x;
  const int p   = tid & 15;        // position 0..15
  const int gg  = tid >> 4;        // channel group 0..15 (8 ch each)

  const int blk = blockIdx.x;      // 8192 = 8 b * 128 h * 8 wt
  const int w0  = (blk & 7) * 16;
  const int h   = (blk >> 3) & 127;
  const int b   = blk >> 10;

  // ---- phase 1: STREAM fm once -> ubuf (f32 u) + vstash (bf16 v) ----
  {
    const float* g = fm + ((size_t)(b * 128 + gg * 8)) * 65536 +
                     (size_t)(2 * h) * 256 + 2 * (w0 + p);
#pragma unroll
    for (int i = 0; i < 8; ++i) {
      const int c = gg * 8 + i;
      const float2 va = *(const float2*)(g);        // row 2h:   v0,v1
      const float2 vb = *(const float2*)(g + 256);  // row 2h+1: v2,v3
      ubuf[c * 17 + p] = (va.x + va.y) + (vb.x + vb.y);
      vstash[c * 33 + 2 * p]     = pack2(va.x, va.y);
      vstash[c * 33 + 2 * p + 1] = pack2(vb.x, vb.y);
      g += 65536;
    }
  }
  __syncthreads();

  // ---- phase 2: GEMM1  Q[r][p] = sum_c WqT'[c][r] * u[c][p] ----
  {
    const int p2 = tid & 15;
    const int rq = (tid >> 4) & 7;   // r-quad base = rq*4
    const int ch = tid >> 7;         // c half 0/1
    float a0 = 0.f, a1 = 0.f, a2 = 0.f, a3 = 0.f;
    const float* wqb = ws + rq * 4;
#pragma unroll 16
    for (int c = ch * 64; c < ch * 64 + 64; ++c) {
      const float u = ubuf[c * 17 + p2];
      const float4 w = *(const float4*)(wqb + c * 32);
      a0 = fmaf(w.x, u, a0);
      a1 = fmaf(w.y, u, a1);
      a2 = fmaf(w.z, u, a2);
      a3 = fmaf(w.w, u, a3);
    }
    Qpart[ch * 544 + (rq * 4 + 0) * 17 + p2] = a0;
    Qpart[ch * 544 + (rq * 4 + 1) * 17 + p2] = a1;
    Qpart[ch * 544 + (rq * 4 + 2) * 17 + p2] = a2;
    Qpart[ch * 544 + (rq * 4 + 3) * 17 + p2] = a3;
  }
  __syncthreads();
  if (tid < 128) {  // combine c-halves: Qpart[0] += Qpart[1]
    const int p2 = tid & 15;
    const int rq = tid >> 4;
#pragma unroll
    for (int j = 0; j < 4; ++j) {
      const int r = rq * 4 + j;
      Qpart[r * 17 + p2] += Qpart[544 + r * 17 + p2];
    }
  }
  __syncthreads();

  // ---- phase 3: fused t + logits (per ch: t = qh.WkT, logits += t*v) ----
  float l0 = 0.f, l1 = 0.f, l2 = 0.f, l3 = 0.f;
  {
    float qh[32];
#pragma unroll
    for (int r = 0; r < 32; ++r) qh[r] = Qpart[r * 17 + p];
    const float* wkb = ws + 4096;
#pragma unroll
    for (int i = 0; i < 8; ++i) {
      const int c = gg * 8 + i;
      float t0 = 0.f, t1 = 0.f;
#pragma unroll
      for (int rr = 0; rr < 32; rr += 4) {
        const float4 k = *(const float4*)(wkb + c * 32 + rr);
        t0 = fmaf(qh[rr + 0], k.x, t0);
        t1 = fmaf(qh[rr + 1], k.y, t1);
        t0 = fmaf(qh[rr + 2], k.z, t0);
        t1 = fmaf(qh[rr + 3], k.w, t1);
      }
      const float tv = t0 + t1;
      const float2 va = unpack2(vstash[c * 33 + 2 * p]);
      const float2 vb = unpack2(vstash[c * 33 + 2 * p + 1]);
      l0 = fmaf(tv, va.x, l0);
      l1 = fmaf(tv, va.y, l1);
      l2 = fmaf(tv, vb.x, l2);
      l3 = fmaf(tv, vb.y, l3);
    }
  }
  *(float4*)(lbuf + gg * 64 + p * 4) = make_float4(l0, l1, l2, l3);
  __syncthreads();

  // ---- phase 4: softmax over s (16 lanes combine the 16 groups) ----
  if (tid < 16) {
    float L0 = 0.f, L1 = 0.f, L2 = 0.f, L3 = 0.f;
#pragma unroll
    for (int k = 0; k < 16; ++k) {
      const float4 s = *(const float4*)(lbuf + k * 64 + tid * 4);
      L0 += s.x; L1 += s.y; L2 += s.z; L3 += s.w;
    }
    const float mx = fmaxf(fmaxf(L0, L1), fmaxf(L2, L3));
    const float e0 = __expf(L0 - mx), e1 = __expf(L1 - mx);
    const float e2 = __expf(L2 - mx), e3 = __expf(L3 - mx);
    const float inv = 1.0f / ((e0 + e1) + (e2 + e3));
    *(float4*)(abuf + tid * 4) =
        make_float4(e0 * inv, e1 * inv, e2 * inv, e3 * inv);
  }
  __syncthreads();

  // ---- phase 5: out = sum_s attn_s * v_s (v from vstash) ----
  {
    const float4 at = *(const float4*)(abuf + p * 4);
    float* op = out + ((size_t)(b * 128 + gg * 8)) * 16384 + h * 128 + w0 + p;
#pragma unroll
    for (int i = 0; i < 8; ++i) {
      const int c = gg * 8 + i;
      const float2 va = unpack2(vstash[c * 33 + 2 * p]);
      const float2 vb = unpack2(vstash[c * 33 + 2 * p + 1]);
      op[(size_t)i * 16384] =
          fmaf(at.x, va.x, fmaf(at.y, va.y, fmaf(at.z, vb.x, at.w * vb.y)));
    }
  }
}

extern "C" void kernel_launch(void* const* d_in, const int* in_sizes, int n_in,
                              void* d_out, int out_size, void* d_ws, size_t ws_size,
                              hipStream_t stream) {
  const float* fm = (const float*)d_in[0];
  const float* Wq = (const float*)d_in[1];
  const float* Wk = (const float*)d_in[2];
  float* outp = (float*)d_out;
  float* ws = (float*)d_ws;

  wt_kernel<<<16, 256, 0, stream>>>(Wq, Wk, ws);
  attn_main<<<8192, 256, 0, stream>>>(fm, ws, outp);
}

// Round 16
// 146.819 us; speedup vs baseline: 2.7082x; 1.2778x over previous
//
#include <hip/hip_runtime.h>
#include <hip/hip_bf16.h>
#include <math.h>

// AttentionDownSample: fm [8,128,256,256] f32, Wq/Wk [32,128] f32
// out [8,128,128,128] f32.
//
// r16: SINGLE fused stream pass. Key algebraic change: accumulate
//   K_s[r,p] = sum_c Wk[r,c] * v_s[c,p]
// in the SAME pass as Q (both linear in fm) -> logits = sum_r Q[r,p]K_s[r,p]
// needs no second fm pass and no V for logits. V stashed bf16 in LDS only
// for the final apply.
// Session lessons baked in:
//   - 64-position tiles: 512 B contiguous per (c,row) — r7's 2.86 TB/s DRAM
//     page locality (32/16-pos tiles measured 1.2/0.9 TB/s).
//   - loads spread over the WHOLE kernel via an 8-channel prefetch ring
//     (~128 B/lane in flight continuously), no load-free phases.
//   - LDS 69 KB -> 2 blocks/CU -> allocator VGPR budget 256 -> the ~90-reg
//     working set cannot spill (r12-proven regime; fighting the heuristic
//     with hints failed in r8/r9/r11/r13).
//   - weights: wave-uniform s_load (r-slice 8/wave); fm: vmcnt vector loads;
//     compiler emits counted waits for both.
// Math: u[c]=v0+v1+v2+v3; Q[rg]=sum_c WqT'[c][rg]u[c] (0.25/sqrt32 folded);
// K as above; logit_s=sum_rg Q K; softmax s=4; out[c]=sum_s attn_s v_s[c].

typedef unsigned int uint32;

__device__ __forceinline__ uint32 pack2(float x, float y) {
  union { __hip_bfloat162 h; uint32 u; } cvt;
  cvt.h = __float22bfloat162_rn(make_float2(x, y));
  return cvt.u;
}
__device__ __forceinline__ float2 unpack2(uint32 u) {
  float2 r;
  r.x = __uint_as_float(u << 16);
  r.y = __uint_as_float(u & 0xffff0000u);
  return r;
}

__global__ __launch_bounds__(256) void wt_kernel(const float* __restrict__ Wq,
                                                 const float* __restrict__ Wk,
                                                 float* __restrict__ ws) {
  int t = blockIdx.x * 256 + threadIdx.x;  // 4096 threads, one (c,r) each
  if (t < 4096) {
    int c = t >> 5, r = t & 31;
    ws[c * 32 + r]        = Wq[r * 128 + c] * (0.25f / sqrtf(32.0f));
    ws[4096 + c * 32 + r] = Wk[r * 128 + c];
  }
}

__global__ __launch_bounds__(256)
void attn_main(const float* __restrict__ fm,
               const float* __restrict__ ws,
               float* __restrict__ out) {
  __shared__ uint2 stash[128][64];   // 64 KB: v[c][p] as 2x bf16x2
  __shared__ float lbuf[4][64][4];   // 4 KB: per-wave partial logits
  __shared__ float abuf[64][4];      // 1 KB: attn weights

  const int tid = threadIdx.x;
  const int p   = tid & 63;                                  // position 0..63
  const int w   = __builtin_amdgcn_readfirstlane(tid >> 6);  // wave 0..3

  const int blk = blockIdx.x;      // 2048 = 8 b * 128 h * 2 wt
  const int w0  = (blk & 1) * 64;
  const int h   = (blk >> 1) & 127;
  const int b   = blk >> 8;

  const float* g = fm + ((size_t)(b * 128)) * 65536 +
                   (size_t)(2 * h) * 256 + 2 * (w0 + p);
  const float* wq = ws + 8 * w;          // WqT'[c][8w + r], wave-uniform
  const float* wk = ws + 4096 + 8 * w;   // WkT[c][8w + r]

  // ---- single fused stream: fm read ONCE, Q+K accumulate, v -> stash ----
  float Kacc[8][4];
  float Qacc[8];
#pragma unroll
  for (int r = 0; r < 8; ++r) {
    Qacc[r] = 0.f;
    Kacc[r][0] = Kacc[r][1] = Kacc[r][2] = Kacc[r][3] = 0.f;
  }

  float2 ra[8], rb[8];  // 8-channel prefetch ring
#pragma unroll
  for (int i = 0; i < 8; ++i) {
    ra[i] = *(const float2*)(g + (size_t)i * 65536);
    rb[i] = *(const float2*)(g + (size_t)i * 65536 + 256);
  }

  for (int c0 = 0; c0 < 128; c0 += 8) {
    const bool pf = (c0 < 120);
#pragma unroll
    for (int j = 0; j < 8; ++j) {
      const int c = c0 + j;
      const float2 va = ra[j];
      const float2 vb = rb[j];
      if (pf) {
        ra[j] = *(const float2*)(g + (size_t)(c + 8) * 65536);
        rb[j] = *(const float2*)(g + (size_t)(c + 8) * 65536 + 256);
      }
      stash[c][p] = make_uint2(pack2(va.x, va.y), pack2(vb.x, vb.y));
      const float u = (va.x + va.y) + (vb.x + vb.y);
#pragma unroll
      for (int r = 0; r < 8; ++r) {
        const float wqv = wq[c * 32 + r];  // s_load, wave-uniform
        const float wkv = wk[c * 32 + r];
        Qacc[r] = fmaf(wqv, u, Qacc[r]);
        Kacc[r][0] = fmaf(wkv, va.x, Kacc[r][0]);
        Kacc[r][1] = fmaf(wkv, va.y, Kacc[r][1]);
        Kacc[r][2] = fmaf(wkv, vb.x, Kacc[r][2]);
        Kacc[r][3] = fmaf(wkv, vb.y, Kacc[r][3]);
      }
    }
  }

  // ---- per-wave partial logits over its r-slice ----
  {
    float pl0 = 0.f, pl1 = 0.f, pl2 = 0.f, pl3 = 0.f;
#pragma unroll
    for (int r = 0; r < 8; ++r) {
      pl0 = fmaf(Qacc[r], Kacc[r][0], pl0);
      pl1 = fmaf(Qacc[r], Kacc[r][1], pl1);
      pl2 = fmaf(Qacc[r], Kacc[r][2], pl2);
      pl3 = fmaf(Qacc[r], Kacc[r][3], pl3);
    }
    *(float4*)&lbuf[w][p][0] = make_float4(pl0, pl1, pl2, pl3);
  }
  __syncthreads();

  // ---- combine partials + softmax (one wave) ----
  if (tid < 64) {
    const float4 s0 = *(const float4*)&lbuf[0][tid][0];
    const float4 s1 = *(const float4*)&lbuf[1][tid][0];
    const float4 s2 = *(const float4*)&lbuf[2][tid][0];
    const float4 s3 = *(const float4*)&lbuf[3][tid][0];
    const float L0 = (s0.x + s1.x) + (s2.x + s3.x);
    const float L1 = (s0.y + s1.y) + (s2.y + s3.y);
    const float L2 = (s0.z + s1.z) + (s2.z + s3.z);
    const float L3 = (s0.w + s1.w) + (s2.w + s3.w);
    const float mx = fmaxf(fmaxf(L0, L1), fmaxf(L2, L3));
    const float e0 = __expf(L0 - mx), e1 = __expf(L1 - mx);
    const float e2 = __expf(L2 - mx), e3 = __expf(L3 - mx);
    const float inv = 1.0f / ((e0 + e1) + (e2 + e3));
    *(float4*)&abuf[tid][0] =
        make_float4(e0 * inv, e1 * inv, e2 * inv, e3 * inv);
  }
  __syncthreads();

  // ---- apply from stash -> out (wave w: channels 32w..32w+31) ----
  {
    const float4 at = *(const float4*)&abuf[p][0];
    const int cb = 32 * w;
    float* op = out + ((size_t)(b * 128 + cb)) * 16384 + h * 128 + w0 + p;
#pragma unroll 8
    for (int i = 0; i < 32; ++i) {
      const uint2 q = stash[cb + i][p];
      const float2 va = unpack2(q.x);
      const float2 vb = unpack2(q.y);
      op[(size_t)i * 16384] =
          fmaf(at.x, va.x, fmaf(at.y, va.y, fmaf(at.z, vb.x, at.w * vb.y)));
    }
  }
}

extern "C" void kernel_launch(void* const* d_in, const int* in_sizes, int n_in,
                              void* d_out, int out_size, void* d_ws, size_t ws_size,
                              hipStream_t stream) {
  const float* fm = (const float*)d_in[0];
  const float* Wq = (const float*)d_in[1];
  const float* Wk = (const float*)d_in[2];
  float* outp = (float*)d_out;
  float* ws = (float*)d_ws;

  wt_kernel<<<16, 256, 0, stream>>>(Wq, Wk, ws);
  attn_main<<<2048, 256, 0, stream>>>(fm, ws, outp);
}